// Round 3
// baseline (240.313 us; speedup 1.0000x reference)
//
#include <hip/hip_runtime.h>

// ---------------------------------------------------------------------------
// minerva_35124242547419 — R12: proj = W-in-registers, no Ws LDS.
// R11 counters: proj 60us @ MfmaUtil 5.6 / VALU 5.8 / HBM 11.5 / occ 11 ->
// latency/convoy-bound: 32KB Ws LDS-DMA drained at a barrier each iter with
// only 8 waves/CU; 74KB LDS -> 2 blk/CU -> 25% tail on grid 640.
// Fix: each wave reads a PRIVATE 64-col W strip -> B-fragments load directly
// global->VGPR from row-major bf16 W2 (L2-resident, compiler-scheduled,
// barrier-free). LDS = Xs dbuf only (17.6KB) -> 3 blk/CU, all 640 resident.
// Also: write_loss fused into finalize (last-block pattern). fused_sim kept
// from R11 (deferred-drain pipeline).
// I/O contract (R4-R6): f32 inputs resolved BY SIZE, f32 output.
// ---------------------------------------------------------------------------

typedef __bf16 bf16x8 __attribute__((ext_vector_type(8)));
typedef __bf16 bf16x4 __attribute__((ext_vector_type(4)));
typedef float  f32x4  __attribute__((ext_vector_type(4)));

__device__ __forceinline__ f32x4 f4zero() { f32x4 z = {0.f, 0.f, 0.f, 0.f}; return z; }

__device__ __forceinline__ f32x4 mfma16(bf16x8 a, bf16x8 b, f32x4 c) {
  return __builtin_amdgcn_mfma_f32_16x16x32_bf16(a, b, c, 0, 0, 0);
}

// 8 consecutive f32 -> bf16x8
__device__ __forceinline__ bf16x8 load8f(const float* p) {
  f32x4 a = *(const f32x4*)p;
  f32x4 b = *(const f32x4*)(p + 4);
  bf16x8 r;
  r[0] = (__bf16)a[0]; r[1] = (__bf16)a[1]; r[2] = (__bf16)a[2]; r[3] = (__bf16)a[3];
  r[4] = (__bf16)b[0]; r[5] = (__bf16)b[1]; r[6] = (__bf16)b[2]; r[7] = (__bf16)b[3];
  return r;
}

__device__ __forceinline__ bf16x8 cvt2(f32x4 a, f32x4 b) {
  bf16x8 r;
  r[0] = (__bf16)a[0]; r[1] = (__bf16)a[1]; r[2] = (__bf16)a[2]; r[3] = (__bf16)a[3];
  r[4] = (__bf16)b[0]; r[5] = (__bf16)b[1]; r[6] = (__bf16)b[2]; r[7] = (__bf16)b[3];
  return r;
}

// async 16B global -> LDS (wave-uniform base + lane*16 dest; per-lane gsrc)
__device__ __forceinline__ void async16(const void* g, void* l) {
  __builtin_amdgcn_global_load_lds(
      (const __attribute__((address_space(1))) unsigned int*)g,
      (__attribute__((address_space(3))) unsigned int*)l, 16, 0, 0);
}

// raw barrier helpers (fused_sim pipeline)
__device__ __forceinline__ void bar_lgkm() {
  asm volatile("s_waitcnt lgkmcnt(0)" ::: "memory");
  __builtin_amdgcn_s_barrier();
}
__device__ __forceinline__ void bar_all() {
  asm volatile("s_waitcnt vmcnt(0) lgkmcnt(0)" ::: "memory");
  __builtin_amdgcn_s_barrier();
}

__global__ void fill_sentinel(float* __restrict__ out, int n) {
  for (int i = blockIdx.x * 256 + threadIdx.x; i < n; i += gridDim.x * 256) out[i] = -1.0f;
}

// ---------------------------------------------------------------------------
// prep: one launch for (a) build_vt, (b) W f32->bf16 row-major, (c) zeroing.
//  blocks [0,64):   vT[j][e] = l1norm_row(ex_classes)[e][j], rows 28..31 = 0
//  blocks [64,192): W2 = bf16(W), plain row-major [256][1024]
//  blocks [192,720): zero tT / r_acc / loss+counter
// ---------------------------------------------------------------------------
__global__ void prep(const float* __restrict__ exc, __bf16* __restrict__ vT,
                     const float* __restrict__ W, __bf16* __restrict__ W2,
                     float* __restrict__ zp, int zn) {
  const int b = blockIdx.x, tid = threadIdx.x;
  if (b < 64) {
    int e = b * 256 + tid;
    float m[28];
    float s = 0.f;
#pragma unroll
    for (int j = 0; j < 28; j++) {
      m[j] = exc[(size_t)e * 28 + j];
      s += fabsf(m[j]);
    }
    float inv = 1.0f / fmaxf(s, 1e-12f);
#pragma unroll
    for (int j = 0; j < 28; j++) vT[(size_t)j * 16384 + e] = (__bf16)(m[j] * inv);
#pragma unroll
    for (int j = 28; j < 32; j++) vT[(size_t)j * 16384 + e] = (__bf16)0.0f;
  } else if (b < 192) {
    int i = (b - 64) * 256 + tid;  // 0..32767, 8-elem chunk id (row-major linear)
    *(bf16x8*)(W2 + (size_t)i * 8) = load8f(W + (size_t)i * 8);
  } else {
    for (int i = (b - 192) * 256 + tid; i < zn; i += (gridDim.x - 192) * 256) zp[i] = 0.f;
  }
}

// ---------------------------------------------------------------------------
// P = l2norm_rows(X @ W^T). Block: 32 rows x 256 cols. BK=128, 8 k-iters.
// Wave w owns output cols [w*64, w*64+64): its W strip is PRIVATE ->
// B-fragments stream global->VGPR from row-major bf16 W2 (no LDS, no
// barrier, compiler-pipelined; W2 is 512KB = L2-resident).
// Xs: [2][32][136] bf16 dbuf, reg-prefetch + cvt + ds_write, 1 barrier/iter.
// LDS 17.6 KB -> 3 blk/CU; grid 640 fully resident (capacity 768), no tail.
// blocks 0..511 -> ex_features, 512..639 -> features.
// ---------------------------------------------------------------------------
__global__ __launch_bounds__(256, 3)
void proj_l2norm(const float* __restrict__ Xa, const float* __restrict__ Xb,
                 const __bf16* __restrict__ W2,
                 __bf16* __restrict__ Pa, __bf16* __restrict__ Pb) {
  __shared__ __align__(16) __bf16 Xs[2][32 * 136];  // 17.4 KB
  __shared__ float nrmW[4 * 32];
  __shared__ float invn[32];

  const int tid = threadIdx.x;
  const int w = tid >> 6, lane = tid & 63;
  const int quad = lane >> 4, l15 = lane & 15;
  // Xs staging: 512 chunks/buffer (32 rows x 16 chunks), 2 per thread:
  // chunk idx {tid, tid+256} -> rows {tid>>4, (tid>>4)+16}, col chunk tid&15
  const int srow = tid >> 4, sc = tid & 15;

  const float* X;
  __bf16* P;
  int row0;
  if (blockIdx.x < 512) { X = Xa; P = Pa; row0 = blockIdx.x * 32; }
  else                  { X = Xb; P = Pb; row0 = (blockIdx.x - 512) * 32; }

  const float* xp0 = X + (size_t)(row0 + srow) * 1024 + sc * 8;        // row srow
  const float* xp1 = xp0 + (size_t)16 * 1024;                          // row srow+16

  // prologue: stage Xs[0] for kb=0
  *(bf16x8*)(&Xs[0][srow * 136 + sc * 8])        = load8f(xp0);
  *(bf16x8*)(&Xs[0][(srow + 16) * 136 + sc * 8]) = load8f(xp1);

  f32x4 acc[2][4];
#pragma unroll
  for (int i = 0; i < 2; i++)
#pragma unroll
    for (int j = 0; j < 4; j++) acc[i][j] = f4zero();

  // wave-private W strip base (row-major [256][1024] bf16)
  const __bf16* wstrip = W2 + (size_t)(w * 64) * 1024;

  __syncthreads();

  int cur = 0;
  for (int kb = 0; kb < 8; kb++) {
    const int nxt = cur ^ 1;
    // prefetch next X slab to regs (flies across compute)
    f32x4 p00, p01, p10, p11;
    if (kb < 7) {
      const float* q0 = xp0 + (kb + 1) * 128;
      const float* q1 = xp1 + (kb + 1) * 128;
      p00 = *(const f32x4*)q0; p01 = *(const f32x4*)(q0 + 4);
      p10 = *(const f32x4*)q1; p11 = *(const f32x4*)(q1 + 4);
    }
    // compute: 4 ksub x (2 af ds_read + 4 bfr global + 8 MFMA)
    const __bf16* wk = wstrip + kb * 128;
#pragma unroll
    for (int ksub = 0; ksub < 4; ksub++) {
      bf16x8 af[2], bfr[4];
#pragma unroll
      for (int mb = 0; mb < 2; mb++)
        af[mb] = *(bf16x8*)(&Xs[cur][(mb * 16 + l15) * 136 + ksub * 32 + quad * 8]);
#pragma unroll
      for (int nb = 0; nb < 4; nb++)
        bfr[nb] = *(const bf16x8*)(wk + (size_t)(nb * 16 + l15) * 1024 + ksub * 32 + quad * 8);
#pragma unroll
      for (int mb = 0; mb < 2; mb++)
#pragma unroll
        for (int nb = 0; nb < 4; nb++)
          acc[mb][nb] = mfma16(af[mb], bfr[nb], acc[mb][nb]);
    }
    if (kb < 7) {
      *(bf16x8*)(&Xs[nxt][srow * 136 + sc * 8])        = cvt2(p00, p01);
      *(bf16x8*)(&Xs[nxt][(srow + 16) * 136 + sc * 8]) = cvt2(p10, p11);
    }
    __syncthreads();
    cur = nxt;
  }

  // row sum-of-squares: in-lane over nb, shfl over l15, cross-wave via LDS
  float part[2][4];
#pragma unroll
  for (int mb = 0; mb < 2; mb++)
#pragma unroll
    for (int r = 0; r < 4; r++) {
      float s = 0.f;
#pragma unroll
      for (int nb = 0; nb < 4; nb++) { float v = acc[mb][nb][r]; s += v * v; }
      part[mb][r] = s;
    }
#pragma unroll
  for (int m = 1; m < 16; m <<= 1)
#pragma unroll
    for (int mb = 0; mb < 2; mb++)
#pragma unroll
      for (int r = 0; r < 4; r++) part[mb][r] += __shfl_xor(part[mb][r], m, 64);

  if (l15 == 0) {
#pragma unroll
    for (int mb = 0; mb < 2; mb++)
#pragma unroll
      for (int r = 0; r < 4; r++)
        nrmW[w * 32 + mb * 16 + quad * 4 + r] = part[mb][r];
  }
  __syncthreads();
  if (tid < 32) {
    float s = nrmW[tid] + nrmW[32 + tid] + nrmW[64 + tid] + nrmW[96 + tid];
    invn[tid] = 1.0f / fmaxf(sqrtf(s), 1e-12f);
  }
  __syncthreads();
#pragma unroll
  for (int mb = 0; mb < 2; mb++)
#pragma unroll
    for (int nb = 0; nb < 4; nb++)
#pragma unroll
      for (int r = 0; r < 4; r++) {
        int row = mb * 16 + quad * 4 + r;
        int col = w * 64 + nb * 16 + l15;
        P[(size_t)(row0 + row) * 256 + col] = (__bf16)(acc[mb][nb][r] * invn[row]);
      }
}

// ---------------------------------------------------------------------------
// Fused flash-style pass (unchanged from R11: deferred-drain pipeline).
// Per t-iter: QK(t) | lgkm-bar | issue DMA Ks(t+1),Vs(t+1) | Us write |
// lgkm-bar | PV(t) | vmcnt0-bar.
// ---------------------------------------------------------------------------
__global__ __launch_bounds__(256, 2)
void fused_sim(const __bf16* __restrict__ fn, const __bf16* __restrict__ efn,
               const __bf16* __restrict__ vTg,
               float* __restrict__ tT, float* __restrict__ r_acc) {
  __shared__ __align__(16) __bf16 Ks[64 * 256];    // 32 KB, swizzled
  __shared__ __align__(16) __bf16 Vs[2][32 * 64];  // 8 KB, swizzled, dbuf
  __shared__ __align__(16) __bf16 Us[128 * 72];    // 18 KB

  const int tid = threadIdx.x, w = tid >> 6, lane = tid & 63;
  const int quad = lane >> 4, l15 = lane & 15;
  const int wy = w >> 1, wx = w & 1;
  const int swk = l15 & 7;
  const int chunk = blockIdx.x & 15, mtile = blockIdx.x >> 4;
  const int q0 = mtile * 128;
  const int e_base = chunk * 1024;

  int koff[8];
#pragma unroll
  for (int rep = 0; rep < 8; rep++) {
    int idx = rep * 256 + tid;     // row = idx>>5, chunk c5' = idx&31
    int row = idx >> 5;
    int c5  = (idx & 31) ^ (row & 7);
    koff[rep] = row * 256 + c5 * 8;
  }
  const int vrow = tid >> 3;
  const int vcs  = (tid & 7) ^ (vrow & 7);
  const size_t vsrc0 = (size_t)vrow * 16384 + e_base + vcs * 8;

  {
    const __bf16* src = efn + (size_t)e_base * 256;
#pragma unroll
    for (int rep = 0; rep < 8; rep++) async16(src + koff[rep], Ks + (rep * 256 + tid) * 8);
    async16(vTg + vsrc0, &Vs[0][tid * 8]);
  }

  bf16x8 qf[8][4];
#pragma unroll
  for (int ks = 0; ks < 8; ks++)
#pragma unroll
    for (int nb = 0; nb < 4; nb++)
      qf[ks][nb] = *(const bf16x8*)(fn + (size_t)(q0 + wx * 64 + nb * 16 + l15) * 256 +
                                    ks * 32 + quad * 8);

  float r_part[4] = {0.f, 0.f, 0.f, 0.f};
  f32x4 accp[2][2];
#pragma unroll
  for (int a = 0; a < 2; a++)
#pragma unroll
    for (int b = 0; b < 2; b++) accp[a][b] = f4zero();

  bar_all();  // Ks(0), Vs(0), qf ready

  int cur = 0;
  for (int t = 0; t < 16; t++) {
    // ---- QK: reads Ks ----
    f32x4 accs[2][4];
#pragma unroll
    for (int a = 0; a < 2; a++)
#pragma unroll
      for (int b = 0; b < 4; b++) accs[a][b] = f4zero();
#pragma unroll
    for (int ks = 0; ks < 8; ks++) {
      bf16x8 af[2];
#pragma unroll
      for (int mb = 0; mb < 2; mb++)
        af[mb] = *(bf16x8*)(Ks + (wy * 32 + mb * 16 + l15) * 256 +
                            ((ks * 4 + quad) ^ swk) * 8);
#pragma unroll
      for (int mb = 0; mb < 2; mb++)
#pragma unroll
        for (int nb = 0; nb < 4; nb++)
          accs[mb][nb] = mfma16(af[mb], qf[ks][nb], accs[mb][nb]);
    }

    bar_lgkm();  // all waves done reading Ks -> safe to overwrite via DMA

    if (t < 15) {
      const __bf16* src = efn + (size_t)(e_base + (t + 1) * 64) * 256;
#pragma unroll
      for (int rep = 0; rep < 8; rep++)
        async16(src + koff[rep], Ks + (rep * 256 + tid) * 8);
      async16(vTg + vsrc0 + (t + 1) * 64, &Vs[cur ^ 1][tid * 8]);
    }

    // ---- Us write (power-sign + |.| partial) ----
#pragma unroll
    for (int mb = 0; mb < 2; mb++) {
      const int eo = wy * 32 + mb * 16 + quad * 4;
#pragma unroll
      for (int nb = 0; nb < 4; nb++) {
        const int q = wx * 64 + nb * 16 + l15;
        bf16x4 pk;
#pragma unroll
        for (int r = 0; r < 4; r++) {
          float s = accs[mb][nb][r];
          __bf16 ub = (__bf16)(s * s * s);
          pk[r] = ub;
          r_part[nb] += fabsf((float)ub);
        }
        *(bf16x4*)(Us + q * 72 + eo) = pk;
      }
    }

    bar_lgkm();  // Us visible

    // ---- PV: reads Us + Vs[cur] ----
#pragma unroll
    for (int ks = 0; ks < 2; ks++) {
      bf16x8 vf[2], uf[2];
#pragma unroll
      for (int cb = 0; cb < 2; cb++)
        vf[cb] = *(bf16x8*)(&Vs[cur][(cb * 16 + l15) * 64 + ((ks * 4 + quad) ^ swk) * 8]);
#pragma unroll
      for (int qb = 0; qb < 2; qb++)
        uf[qb] = *(bf16x8*)(Us + (w * 32 + qb * 16 + l15) * 72 + ks * 32 + quad * 8);
#pragma unroll
      for (int cb = 0; cb < 2; cb++)
#pragma unroll
        for (int qb = 0; qb < 2; qb++)
          accp[cb][qb] = mfma16(vf[cb], uf[qb], accp[cb][qb]);
    }

    bar_all();  // Ks(t+1)/Vs(t+1) landed, PV reads retired
    cur ^= 1;
  }

#pragma unroll
  for (int nb = 0; nb < 4; nb++) {
    float v = r_part[nb];
    v += __shfl_xor(v, 16, 64);
    v += __shfl_xor(v, 32, 64);
    if (quad == 0) atomicAdd(&r_acc[q0 + wx * 64 + nb * 16 + l15], v);
  }
#pragma unroll
  for (int cb = 0; cb < 2; cb++)
#pragma unroll
    for (int qb = 0; qb < 2; qb++)
#pragma unroll
      for (int r = 0; r < 4; r++)
        atomicAdd(&tT[(size_t)(cb * 16 + quad * 4 + r) * 4096 + q0 + w * 32 + qb * 16 + l15],
                  accp[cb][qb][r]);
}

// ---------------------------------------------------------------------------
// finalize: WAVE-PER-QUERY + fused loss write (last-block pattern).
// loss_acc[0] = loss sum (float); ((unsigned*)loss_acc)[1] = done counter.
// ---------------------------------------------------------------------------
__global__ __launch_bounds__(256, 4)
void finalize(const float* __restrict__ tT, const float* __restrict__ r_acc,
              const float* __restrict__ creps, const float* __restrict__ labels,
              float* __restrict__ loss_acc, float* __restrict__ out) {
  __shared__ __align__(16) float cr[28 * 64];
  __shared__ float wsum[4];
  const int tid = threadIdx.x, w = tid >> 6, lane = tid & 63;
  for (int i = tid; i < 28 * 64; i += 256) cr[i] = creps[i];
  __syncthreads();

  const int q = blockIdx.x * 4 + w;
  float tval = 0.f;
  if (lane < 28) tval = tT[(size_t)lane * 4096 + q];
  tval *= 1.0f / fmaxf(r_acc[q], 1e-12f);

  // echo[c] for c = lane
  float echo = 0.f;
#pragma unroll
  for (int j = 0; j < 28; j++)
    echo = fmaf(__shfl(tval, j, 64), cr[j * 64 + lane], echo);

  float dj = 0.f;
#pragma unroll
  for (int j = 0; j < 28; j++) {
    float df = echo - cr[j * 64 + lane];
    float d2 = df * df;
#pragma unroll
    for (int m = 1; m < 64; m <<= 1) d2 += __shfl_xor(d2, m, 64);
    if (lane == j) dj = sqrtf(d2);
  }

  float lsum = 0.f;
  if (lane < 28) {
    out[1 + (size_t)q * 28 + lane] = -dj;
    float y = labels[(size_t)q * 28 + lane];
    lsum = fmaf(y, dj, log1pf(expf(-dj)));  // BCEWithLogits(-d, y), d >= 0
  }
#pragma unroll
  for (int m = 1; m < 64; m <<= 1) lsum += __shfl_xor(lsum, m, 64);
  if (lane == 0) wsum[w] = lsum;
  __syncthreads();
  if (tid == 0) {
    atomicAdd(loss_acc, wsum[0] + wsum[1] + wsum[2] + wsum[3]);
    __threadfence();
    unsigned* cnt = (unsigned*)(loss_acc + 1);
    unsigned old = atomicAdd(cnt, 1u);
    if (old == gridDim.x - 1) {
      // all blocks' loss adds are device-visible; read via atomic to bypass
      // any stale L1/L2-XCD copy, then publish the scaled mean.
      float total = atomicAdd(loss_acc, 0.0f);
      out[0] = total * (1.0f / 114688.0f);
    }
  }
}

// ---------------------------------------------------------------------------
extern "C" void kernel_launch(void* const* d_in, const int* in_sizes, int n_in,
                              void* d_out, int out_size, void* d_ws, size_t ws_size,
                              hipStream_t stream) {
  // Resolve inputs BY ELEMENT COUNT (unique per input; permutation-proof).
  const float* features = nullptr;  // 4096*1024   = 4194304
  const float* labels   = nullptr;  // 4096*28     = 114688
  const float* ex_feat  = nullptr;  // 16384*1024  = 16777216
  const float* ex_cls   = nullptr;  // 16384*28    = 458752
  const float* g_w      = nullptr;  // 256*1024    = 262144
  const float* creps    = nullptr;  // 28*64       = 1792
  for (int i = 0; i < n_in; i++) {
    switch (in_sizes[i]) {
      case 4194304:  features = (const float*)d_in[i]; break;
      case 114688:   labels   = (const float*)d_in[i]; break;
      case 16777216: ex_feat  = (const float*)d_in[i]; break;
      case 458752:   ex_cls   = (const float*)d_in[i]; break;
      case 262144:   g_w      = (const float*)d_in[i]; break;
      case 1792:     creps    = (const float*)d_in[i]; break;
      default: break;
    }
  }
  float* out = (float*)d_out;  // f32: [loss(1)] ++ [neg_dists 4096*28]

  if (!features || !labels || !ex_feat || !ex_cls || !g_w || !creps ||
      ws_size < (16ull << 20)) {
    fill_sentinel<<<256, 256, 0, stream>>>(out, out_size);  // diagnostic
    return;
  }

  char* ws = (char*)d_ws;
  __bf16* f_n   = (__bf16*)(ws);                    // 2 MB   [4096][256]
  __bf16* ef_n  = (__bf16*)(ws + (2ull << 20));     // 8 MB   [16384][256]
  __bf16* vT    = (__bf16*)(ws + (10ull << 20));    // 1 MB   [32][16384]
  float*  tT    = (float*) (ws + (11ull << 20));    // 512 KB [32][4096]
  float*  r_acc = tT + 32 * 4096;                   // 16 KB
  float*  lossp = r_acc + 4096;                     // 8 B (loss + done-counter)
  __bf16* W2    = (__bf16*)(ws + (12ull << 20));    // 512 KB bf16 W row-major

  prep<<<720, 256, 0, stream>>>(ex_cls, vT, g_w, W2, tT, 32 * 4096 + 4096 + 2);

  proj_l2norm<<<640, 256, 0, stream>>>(ex_feat, features, W2, ef_n, f_n);
  fused_sim<<<512, 256, 0, stream>>>(f_n, ef_n, vT, tT, r_acc);
  finalize<<<1024, 256, 0, stream>>>(tT, r_acc, creps, labels, lossp, out);
}

// Round 4
// 236.881 us; speedup vs baseline: 1.0145x; 1.0145x over previous
//
#include <hip/hip_runtime.h>

// ---------------------------------------------------------------------------
// minerva_35124242547419 — R13: proj = register-pipelined W (2-deep).
// R12 counters: proj 64us @ MfmaUtil 6 / VALU 3.9 / HBM 10.7 / occ 22 ->
// still latency-convoy: per-iter W loads are consumed immediately by MFMA;
// compiler can't hoist next iter's loads across the loop barrier. Fix:
// explicit 2-deep named register double-buffer (wA/wB, static indexing),
// BK=64 (8 bf16x8 = 32 VGPR per buffer). Loads for k+1 issued BEFORE
// compute(k); lgkm-only barriers let them fly across. LDS = Xs dbuf 9.2KB.
// fused_sim (R11 deferred-drain) / prep / finalize unchanged.
// I/O contract (R4-R6): f32 inputs resolved BY SIZE, f32 output.
// ---------------------------------------------------------------------------

typedef __bf16 bf16x8 __attribute__((ext_vector_type(8)));
typedef __bf16 bf16x4 __attribute__((ext_vector_type(4)));
typedef float  f32x4  __attribute__((ext_vector_type(4)));

__device__ __forceinline__ f32x4 f4zero() { f32x4 z = {0.f, 0.f, 0.f, 0.f}; return z; }

__device__ __forceinline__ f32x4 mfma16(bf16x8 a, bf16x8 b, f32x4 c) {
  return __builtin_amdgcn_mfma_f32_16x16x32_bf16(a, b, c, 0, 0, 0);
}

// 8 consecutive f32 -> bf16x8
__device__ __forceinline__ bf16x8 load8f(const float* p) {
  f32x4 a = *(const f32x4*)p;
  f32x4 b = *(const f32x4*)(p + 4);
  bf16x8 r;
  r[0] = (__bf16)a[0]; r[1] = (__bf16)a[1]; r[2] = (__bf16)a[2]; r[3] = (__bf16)a[3];
  r[4] = (__bf16)b[0]; r[5] = (__bf16)b[1]; r[6] = (__bf16)b[2]; r[7] = (__bf16)b[3];
  return r;
}

__device__ __forceinline__ bf16x8 cvt2(f32x4 a, f32x4 b) {
  bf16x8 r;
  r[0] = (__bf16)a[0]; r[1] = (__bf16)a[1]; r[2] = (__bf16)a[2]; r[3] = (__bf16)a[3];
  r[4] = (__bf16)b[0]; r[5] = (__bf16)b[1]; r[6] = (__bf16)b[2]; r[7] = (__bf16)b[3];
  return r;
}

// async 16B global -> LDS (wave-uniform base + lane*16 dest; per-lane gsrc)
__device__ __forceinline__ void async16(const void* g, void* l) {
  __builtin_amdgcn_global_load_lds(
      (const __attribute__((address_space(1))) unsigned int*)g,
      (__attribute__((address_space(3))) unsigned int*)l, 16, 0, 0);
}

// raw barrier helpers: lgkm-only lets global/DMA loads stay in flight.
__device__ __forceinline__ void bar_lgkm() {
  asm volatile("s_waitcnt lgkmcnt(0)" ::: "memory");
  __builtin_amdgcn_s_barrier();
}
__device__ __forceinline__ void bar_all() {
  asm volatile("s_waitcnt vmcnt(0) lgkmcnt(0)" ::: "memory");
  __builtin_amdgcn_s_barrier();
}

__global__ void fill_sentinel(float* __restrict__ out, int n) {
  for (int i = blockIdx.x * 256 + threadIdx.x; i < n; i += gridDim.x * 256) out[i] = -1.0f;
}

// ---------------------------------------------------------------------------
// prep: one launch for (a) build_vt, (b) W f32->bf16 row-major, (c) zeroing.
// ---------------------------------------------------------------------------
__global__ void prep(const float* __restrict__ exc, __bf16* __restrict__ vT,
                     const float* __restrict__ W, __bf16* __restrict__ W2,
                     float* __restrict__ zp, int zn) {
  const int b = blockIdx.x, tid = threadIdx.x;
  if (b < 64) {
    int e = b * 256 + tid;
    float m[28];
    float s = 0.f;
#pragma unroll
    for (int j = 0; j < 28; j++) {
      m[j] = exc[(size_t)e * 28 + j];
      s += fabsf(m[j]);
    }
    float inv = 1.0f / fmaxf(s, 1e-12f);
#pragma unroll
    for (int j = 0; j < 28; j++) vT[(size_t)j * 16384 + e] = (__bf16)(m[j] * inv);
#pragma unroll
    for (int j = 28; j < 32; j++) vT[(size_t)j * 16384 + e] = (__bf16)0.0f;
  } else if (b < 192) {
    int i = (b - 64) * 256 + tid;  // 0..32767, 8-elem chunk id (row-major linear)
    *(bf16x8*)(W2 + (size_t)i * 8) = load8f(W + (size_t)i * 8);
  } else {
    for (int i = (b - 192) * 256 + tid; i < zn; i += (gridDim.x - 192) * 256) zp[i] = 0.f;
  }
}

// ---------------------------------------------------------------------------
// proj helpers: W-tile register load (8 x bf16x8, static idx) + compute.
// ---------------------------------------------------------------------------
__device__ __forceinline__ void loadw8(bf16x8* dst, const __bf16* wbase, int kel,
                                       int l15, int quad) {
#pragma unroll
  for (int i = 0; i < 8; i++) {
    const int ksub = i >> 2, nb = i & 3;
    dst[i] = *(const bf16x8*)(wbase + (size_t)(nb * 16 + l15) * 1024 + kel +
                              ksub * 32 + quad * 8);
  }
}

__device__ __forceinline__ void comp8(const __bf16* Xbuf, const bf16x8* wr,
                                      f32x4 acc[2][4], int l15, int quad) {
#pragma unroll
  for (int ksub = 0; ksub < 2; ksub++) {
    bf16x8 af[2];
#pragma unroll
    for (int mb = 0; mb < 2; mb++)
      af[mb] = *(const bf16x8*)(Xbuf + (mb * 16 + l15) * 72 + ksub * 32 + quad * 8);
#pragma unroll
    for (int mb = 0; mb < 2; mb++)
#pragma unroll
      for (int nb = 0; nb < 4; nb++)
        acc[mb][nb] = mfma16(af[mb], wr[ksub * 4 + nb], acc[mb][nb]);
  }
}

// ---------------------------------------------------------------------------
// P = l2norm_rows(X @ W^T). Block: 32 rows x 256 cols. BK=64, 16 k-iters.
// Wave w owns output cols [w*64,w*64+64): W strip private, streamed
// global->VGPR with a 2-deep named register pipeline (wA/wB): loads for
// iter k+1 issued BEFORE compute(k); vmcnt waits land a full iter later.
// Xs: [2][32][72] bf16 dbuf (9.2 KB), 1 lgkm-barrier/iter.
// blocks 0..511 -> ex_features, 512..639 -> features.
// ---------------------------------------------------------------------------
__global__ __launch_bounds__(256, 3)
void proj_l2norm(const float* __restrict__ Xa, const float* __restrict__ Xb,
                 const __bf16* __restrict__ W2,
                 __bf16* __restrict__ Pa, __bf16* __restrict__ Pb) {
  __shared__ __align__(16) __bf16 Xs[2][32 * 72];  // 9.2 KB
  __shared__ float nrmW[4 * 32];
  __shared__ float invn[32];

  const int tid = threadIdx.x;
  const int w = tid >> 6, lane = tid & 63;
  const int quad = lane >> 4, l15 = lane & 15;
  const int xrow = tid >> 3, xc8 = tid & 7;  // 1 chunk/thread per k-iter

  const float* X;
  __bf16* P;
  int row0;
  if (blockIdx.x < 512) { X = Xa; P = Pa; row0 = blockIdx.x * 32; }
  else                  { X = Xb; P = Pb; row0 = (blockIdx.x - 512) * 32; }

  const float* xsrc = X + (size_t)(row0 + xrow) * 1024 + xc8 * 8;
  const __bf16* wbase = W2 + (size_t)(w * 64) * 1024;

  f32x4 acc[2][4];
#pragma unroll
  for (int i = 0; i < 2; i++)
#pragma unroll
    for (int j = 0; j < 4; j++) acc[i][j] = f4zero();

  bf16x8 wA[8], wB[8];

  // prologue: stage Xs[0](k=0), W regs for k=0
  *(bf16x8*)(&Xs[0][xrow * 72 + xc8 * 8]) = load8f(xsrc);
  loadw8(wA, wbase, 0, l15, quad);
  bar_lgkm();

  for (int kb = 0; kb < 16; kb += 2) {
    // ---- even iter kb: compute(wA, Xs[0]); prefetch k+1 ----
    f32x4 xp0, xp1;
    {
      loadw8(wB, wbase, (kb + 1) * 64, l15, quad);
      const float* xp = xsrc + (kb + 1) * 64;
      xp0 = *(const f32x4*)xp;
      xp1 = *(const f32x4*)(xp + 4);
    }
    comp8(&Xs[0][0], wA, acc, l15, quad);
    *(bf16x8*)(&Xs[1][xrow * 72 + xc8 * 8]) = cvt2(xp0, xp1);
    bar_lgkm();

    // ---- odd iter kb+1: compute(wB, Xs[1]); prefetch k+2 ----
    if (kb + 2 < 16) {
      loadw8(wA, wbase, (kb + 2) * 64, l15, quad);
      const float* xq = xsrc + (kb + 2) * 64;
      xp0 = *(const f32x4*)xq;
      xp1 = *(const f32x4*)(xq + 4);
    }
    comp8(&Xs[1][0], wB, acc, l15, quad);
    if (kb + 2 < 16) {
      *(bf16x8*)(&Xs[0][xrow * 72 + xc8 * 8]) = cvt2(xp0, xp1);
    }
    bar_lgkm();
  }

  // row sum-of-squares: in-lane over nb, shfl over l15, cross-wave via LDS
  float part[2][4];
#pragma unroll
  for (int mb = 0; mb < 2; mb++)
#pragma unroll
    for (int r = 0; r < 4; r++) {
      float s = 0.f;
#pragma unroll
      for (int nb = 0; nb < 4; nb++) { float v = acc[mb][nb][r]; s += v * v; }
      part[mb][r] = s;
    }
#pragma unroll
  for (int m = 1; m < 16; m <<= 1)
#pragma unroll
    for (int mb = 0; mb < 2; mb++)
#pragma unroll
      for (int r = 0; r < 4; r++) part[mb][r] += __shfl_xor(part[mb][r], m, 64);

  if (l15 == 0) {
#pragma unroll
    for (int mb = 0; mb < 2; mb++)
#pragma unroll
      for (int r = 0; r < 4; r++)
        nrmW[w * 32 + mb * 16 + quad * 4 + r] = part[mb][r];
  }
  __syncthreads();
  if (tid < 32) {
    float s = nrmW[tid] + nrmW[32 + tid] + nrmW[64 + tid] + nrmW[96 + tid];
    invn[tid] = 1.0f / fmaxf(sqrtf(s), 1e-12f);
  }
  __syncthreads();
#pragma unroll
  for (int mb = 0; mb < 2; mb++)
#pragma unroll
    for (int nb = 0; nb < 4; nb++)
#pragma unroll
      for (int r = 0; r < 4; r++) {
        int row = mb * 16 + quad * 4 + r;
        int col = w * 64 + nb * 16 + l15;
        P[(size_t)(row0 + row) * 256 + col] = (__bf16)(acc[mb][nb][r] * invn[row]);
      }
}

// ---------------------------------------------------------------------------
// Fused flash-style pass (unchanged from R11: deferred-drain pipeline).
// Per t-iter: QK(t) | lgkm-bar | issue DMA Ks(t+1),Vs(t+1) | Us write |
// lgkm-bar | PV(t) | vmcnt0-bar.
// ---------------------------------------------------------------------------
__global__ __launch_bounds__(256, 2)
void fused_sim(const __bf16* __restrict__ fn, const __bf16* __restrict__ efn,
               const __bf16* __restrict__ vTg,
               float* __restrict__ tT, float* __restrict__ r_acc) {
  __shared__ __align__(16) __bf16 Ks[64 * 256];    // 32 KB, swizzled
  __shared__ __align__(16) __bf16 Vs[2][32 * 64];  // 8 KB, swizzled, dbuf
  __shared__ __align__(16) __bf16 Us[128 * 72];    // 18 KB

  const int tid = threadIdx.x, w = tid >> 6, lane = tid & 63;
  const int quad = lane >> 4, l15 = lane & 15;
  const int wy = w >> 1, wx = w & 1;
  const int swk = l15 & 7;
  const int chunk = blockIdx.x & 15, mtile = blockIdx.x >> 4;
  const int q0 = mtile * 128;
  const int e_base = chunk * 1024;

  int koff[8];
#pragma unroll
  for (int rep = 0; rep < 8; rep++) {
    int idx = rep * 256 + tid;     // row = idx>>5, chunk c5' = idx&31
    int row = idx >> 5;
    int c5  = (idx & 31) ^ (row & 7);
    koff[rep] = row * 256 + c5 * 8;
  }
  const int vrow = tid >> 3;
  const int vcs  = (tid & 7) ^ (vrow & 7);
  const size_t vsrc0 = (size_t)vrow * 16384 + e_base + vcs * 8;

  {
    const __bf16* src = efn + (size_t)e_base * 256;
#pragma unroll
    for (int rep = 0; rep < 8; rep++) async16(src + koff[rep], Ks + (rep * 256 + tid) * 8);
    async16(vTg + vsrc0, &Vs[0][tid * 8]);
  }

  bf16x8 qf[8][4];
#pragma unroll
  for (int ks = 0; ks < 8; ks++)
#pragma unroll
    for (int nb = 0; nb < 4; nb++)
      qf[ks][nb] = *(const bf16x8*)(fn + (size_t)(q0 + wx * 64 + nb * 16 + l15) * 256 +
                                    ks * 32 + quad * 8);

  float r_part[4] = {0.f, 0.f, 0.f, 0.f};
  f32x4 accp[2][2];
#pragma unroll
  for (int a = 0; a < 2; a++)
#pragma unroll
    for (int b = 0; b < 2; b++) accp[a][b] = f4zero();

  bar_all();  // Ks(0), Vs(0), qf ready

  int cur = 0;
  for (int t = 0; t < 16; t++) {
    // ---- QK: reads Ks ----
    f32x4 accs[2][4];
#pragma unroll
    for (int a = 0; a < 2; a++)
#pragma unroll
      for (int b = 0; b < 4; b++) accs[a][b] = f4zero();
#pragma unroll
    for (int ks = 0; ks < 8; ks++) {
      bf16x8 af[2];
#pragma unroll
      for (int mb = 0; mb < 2; mb++)
        af[mb] = *(bf16x8*)(Ks + (wy * 32 + mb * 16 + l15) * 256 +
                            ((ks * 4 + quad) ^ swk) * 8);
#pragma unroll
      for (int mb = 0; mb < 2; mb++)
#pragma unroll
        for (int nb = 0; nb < 4; nb++)
          accs[mb][nb] = mfma16(af[mb], qf[ks][nb], accs[mb][nb]);
    }

    bar_lgkm();  // all waves done reading Ks -> safe to overwrite via DMA

    if (t < 15) {
      const __bf16* src = efn + (size_t)(e_base + (t + 1) * 64) * 256;
#pragma unroll
      for (int rep = 0; rep < 8; rep++)
        async16(src + koff[rep], Ks + (rep * 256 + tid) * 8);
      async16(vTg + vsrc0 + (t + 1) * 64, &Vs[cur ^ 1][tid * 8]);
    }

    // ---- Us write (power-sign + |.| partial) ----
#pragma unroll
    for (int mb = 0; mb < 2; mb++) {
      const int eo = wy * 32 + mb * 16 + quad * 4;
#pragma unroll
      for (int nb = 0; nb < 4; nb++) {
        const int q = wx * 64 + nb * 16 + l15;
        bf16x4 pk;
#pragma unroll
        for (int r = 0; r < 4; r++) {
          float s = accs[mb][nb][r];
          __bf16 ub = (__bf16)(s * s * s);
          pk[r] = ub;
          r_part[nb] += fabsf((float)ub);
        }
        *(bf16x4*)(Us + q * 72 + eo) = pk;
      }
    }

    bar_lgkm();  // Us visible

    // ---- PV: reads Us + Vs[cur] ----
#pragma unroll
    for (int ks = 0; ks < 2; ks++) {
      bf16x8 vf[2], uf[2];
#pragma unroll
      for (int cb = 0; cb < 2; cb++)
        vf[cb] = *(bf16x8*)(&Vs[cur][(cb * 16 + l15) * 64 + ((ks * 4 + quad) ^ swk) * 8]);
#pragma unroll
      for (int qb = 0; qb < 2; qb++)
        uf[qb] = *(bf16x8*)(Us + (w * 32 + qb * 16 + l15) * 72 + ks * 32 + quad * 8);
#pragma unroll
      for (int cb = 0; cb < 2; cb++)
#pragma unroll
        for (int qb = 0; qb < 2; qb++)
          accp[cb][qb] = mfma16(vf[cb], uf[qb], accp[cb][qb]);
    }

    bar_all();  // Ks(t+1)/Vs(t+1) landed, PV reads retired
    cur ^= 1;
  }

#pragma unroll
  for (int nb = 0; nb < 4; nb++) {
    float v = r_part[nb];
    v += __shfl_xor(v, 16, 64);
    v += __shfl_xor(v, 32, 64);
    if (quad == 0) atomicAdd(&r_acc[q0 + wx * 64 + nb * 16 + l15], v);
  }
#pragma unroll
  for (int cb = 0; cb < 2; cb++)
#pragma unroll
    for (int qb = 0; qb < 2; qb++)
#pragma unroll
      for (int r = 0; r < 4; r++)
        atomicAdd(&tT[(size_t)(cb * 16 + quad * 4 + r) * 4096 + q0 + w * 32 + qb * 16 + l15],
                  accp[cb][qb][r]);
}

// ---------------------------------------------------------------------------
// finalize: WAVE-PER-QUERY + fused loss write (last-block pattern).
// ---------------------------------------------------------------------------
__global__ __launch_bounds__(256, 4)
void finalize(const float* __restrict__ tT, const float* __restrict__ r_acc,
              const float* __restrict__ creps, const float* __restrict__ labels,
              float* __restrict__ loss_acc, float* __restrict__ out) {
  __shared__ __align__(16) float cr[28 * 64];
  __shared__ float wsum[4];
  const int tid = threadIdx.x, w = tid >> 6, lane = tid & 63;
  for (int i = tid; i < 28 * 64; i += 256) cr[i] = creps[i];
  __syncthreads();

  const int q = blockIdx.x * 4 + w;
  float tval = 0.f;
  if (lane < 28) tval = tT[(size_t)lane * 4096 + q];
  tval *= 1.0f / fmaxf(r_acc[q], 1e-12f);

  // echo[c] for c = lane
  float echo = 0.f;
#pragma unroll
  for (int j = 0; j < 28; j++)
    echo = fmaf(__shfl(tval, j, 64), cr[j * 64 + lane], echo);

  float dj = 0.f;
#pragma unroll
  for (int j = 0; j < 28; j++) {
    float df = echo - cr[j * 64 + lane];
    float d2 = df * df;
#pragma unroll
    for (int m = 1; m < 64; m <<= 1) d2 += __shfl_xor(d2, m, 64);
    if (lane == j) dj = sqrtf(d2);
  }

  float lsum = 0.f;
  if (lane < 28) {
    out[1 + (size_t)q * 28 + lane] = -dj;
    float y = labels[(size_t)q * 28 + lane];
    lsum = fmaf(y, dj, log1pf(expf(-dj)));  // BCEWithLogits(-d, y), d >= 0
  }
#pragma unroll
  for (int m = 1; m < 64; m <<= 1) lsum += __shfl_xor(lsum, m, 64);
  if (lane == 0) wsum[w] = lsum;
  __syncthreads();
  if (tid == 0) {
    atomicAdd(loss_acc, wsum[0] + wsum[1] + wsum[2] + wsum[3]);
    __threadfence();
    unsigned* cnt = (unsigned*)(loss_acc + 1);
    unsigned old = atomicAdd(cnt, 1u);
    if (old == gridDim.x - 1) {
      float total = atomicAdd(loss_acc, 0.0f);
      out[0] = total * (1.0f / 114688.0f);
    }
  }
}

// ---------------------------------------------------------------------------
extern "C" void kernel_launch(void* const* d_in, const int* in_sizes, int n_in,
                              void* d_out, int out_size, void* d_ws, size_t ws_size,
                              hipStream_t stream) {
  // Resolve inputs BY ELEMENT COUNT (unique per input; permutation-proof).
  const float* features = nullptr;  // 4096*1024   = 4194304
  const float* labels   = nullptr;  // 4096*28     = 114688
  const float* ex_feat  = nullptr;  // 16384*1024  = 16777216
  const float* ex_cls   = nullptr;  // 16384*28    = 458752
  const float* g_w      = nullptr;  // 256*1024    = 262144
  const float* creps    = nullptr;  // 28*64       = 1792
  for (int i = 0; i < n_in; i++) {
    switch (in_sizes[i]) {
      case 4194304:  features = (const float*)d_in[i]; break;
      case 114688:   labels   = (const float*)d_in[i]; break;
      case 16777216: ex_feat  = (const float*)d_in[i]; break;
      case 458752:   ex_cls   = (const float*)d_in[i]; break;
      case 262144:   g_w      = (const float*)d_in[i]; break;
      case 1792:     creps    = (const float*)d_in[i]; break;
      default: break;
    }
  }
  float* out = (float*)d_out;  // f32: [loss(1)] ++ [neg_dists 4096*28]

  if (!features || !labels || !ex_feat || !ex_cls || !g_w || !creps ||
      ws_size < (16ull << 20)) {
    fill_sentinel<<<256, 256, 0, stream>>>(out, out_size);  // diagnostic
    return;
  }

  char* ws = (char*)d_ws;
  __bf16* f_n   = (__bf16*)(ws);                    // 2 MB   [4096][256]
  __bf16* ef_n  = (__bf16*)(ws + (2ull << 20));     // 8 MB   [16384][256]
  __bf16* vT    = (__bf16*)(ws + (10ull << 20));    // 1 MB   [32][16384]
  float*  tT    = (float*) (ws + (11ull << 20));    // 512 KB [32][4096]
  float*  r_acc = tT + 32 * 4096;                   // 16 KB
  float*  lossp = r_acc + 4096;                     // 8 B (loss + done-counter)
  __bf16* W2    = (__bf16*)(ws + (12ull << 20));    // 512 KB bf16 W row-major

  prep<<<720, 256, 0, stream>>>(ex_cls, vT, g_w, W2, tT, 32 * 4096 + 4096 + 2);

  proj_l2norm<<<640, 256, 0, stream>>>(ex_feat, features, W2, ef_n, f_n);
  fused_sim<<<512, 256, 0, stream>>>(f_n, ef_n, vT, tT, r_acc);
  finalize<<<1024, 256, 0, stream>>>(tT, r_acc, creps, labels, lossp, out);
}